// Round 7
// baseline (311.701 us; speedup 1.0000x reference)
//
#include <hip/hip_runtime.h>
#include <math.h>

#define NNODES 30000
#define MPAD   30080          // padded Z row count per relation (470*64)
#define NEDGES 300000
#define NREL 3
#define IND 256
#define HIDD 32
#define OUTD 64
#define NHEADS 4
#define C1 (NHEADS*HIDD)    // 128
#define C2 (NHEADS*OUTD)    // 256
#define NEG_SLOPE 0.2f
#define CAP 64              // max in-degree per (rel,node); Poisson(10) -> P(>=64) ~ 1e-30

typedef short bf16x8 __attribute__((ext_vector_type(8)));
typedef float f32x4  __attribute__((ext_vector_type(4)));
typedef float f32x2  __attribute__((ext_vector_type(2)));   // -> v_pk_fma_f32

// ---- bf16 <-> f32 helpers (RNE pack; exact unpack) ----
__device__ __forceinline__ float b2f(unsigned short u) {
    return __uint_as_float(((unsigned)u) << 16);
}
__device__ __forceinline__ unsigned short f2b(float f) {
    unsigned u = __float_as_uint(f);
    u += 0x7fffu + ((u >> 16) & 1u);     // round-to-nearest-even
    return (unsigned short)(u >> 16);
}

// ---- DPP wave64 sum: VALU-pipe reduction (NO ds_swizzle -> no LDS-unit pressure) ----
// row_shr:1,2,4,8 then row_bcast15, row_bcast31; lane 63 ends with the full sum.
template<int CTRL>
__device__ __forceinline__ float dppadd(float x) {
    int s = __builtin_amdgcn_update_dpp(0, __float_as_int(x), CTRL, 0xf, 0xf, true);
    return x + __int_as_float(s);
}
__device__ __forceinline__ float dpp_wsum63(float x) {
    x = dppadd<0x111>(x);    // row_shr:1
    x = dppadd<0x112>(x);    // row_shr:2
    x = dppadd<0x114>(x);    // row_shr:4
    x = dppadd<0x118>(x);    // row_shr:8  -> lane15/31/47/63 hold row sums
    x = dppadd<0x142>(x);    // row_bcast15 -> lane31/63 hold half sums
    x = dppadd<0x143>(x);    // row_bcast31 -> lane63 holds full sum
    return x;
}
// wave-uniform 1/sum (rcp is 1-ulp; denominator is a sum of positives)
__device__ __forceinline__ float wave_rcp_sum(float w) {
    float den = __uint_as_float(__builtin_amdgcn_readlane(
        __float_as_uint(dpp_wsum63(w)), 63));
    return __builtin_amdgcn_rcpf(den);
}

// ---- pack W[r] (row-major KxN fp32) into MFMA B-fragment order, bf16 ----
// frag fid = (r*NT + nt)*KS + ks; lane l holds B[ks*32 + (l>>4)*8 + j][nt*16 + (l&15)]
template<int K, int N>
__device__ __forceinline__ void pack_w_dev(const float* __restrict__ W,
                                           unsigned short* __restrict__ P, int t) {
    const int KS = K / 32, NT = N / 16;
    int lane = t & 63;
    int fid = t >> 6;
    if (fid >= NREL * NT * KS) return;
    int ks = fid % KS;
    int nt = (fid / KS) % NT;
    int r  = fid / (KS * NT);
    int n  = nt * 16 + (lane & 15);
    int k0 = ks * 32 + (lane >> 4) * 8;
    const float* Wr = W + (size_t)r * K * N;
    unsigned short o[8];
#pragma unroll
    for (int j = 0; j < 8; j++) o[j] = f2b(Wr[(size_t)(k0 + j) * N + n]);
    unsigned short* dst = P + (size_t)fid * 512 + lane * 8;
    *(ushort4*)&dst[0] = *(ushort4*)&o[0];
    *(ushort4*)&dst[4] = *(ushort4*)&o[4];
}

// ---- pack V[r] (K=512 x N=64) B-frags, where V[r][h*128+c][n] = W2[r][c][h*64+n] ----
//   out[n,nn] = (1/4) * sum_r agg_r[n, h*128+c] * V[r][h*128+c][nn]
__device__ __forceinline__ void pack_v_dev(const float* __restrict__ W2,
                                           unsigned short* __restrict__ P, int t) {
    const int KS = 16, NT = 4;   // K=512, N=64
    int lane = t & 63;
    int fid = t >> 6;
    if (fid >= NREL * NT * KS) return;
    int ks = fid % KS;
    int nt = (fid / KS) % NT;
    int r  = fid / (KS * NT);
    int n  = nt * 16 + (lane & 15);
    int k0 = ks * 32 + (lane >> 4) * 8;
    const float* Wr = W2 + (size_t)r * C1 * C2;
    unsigned short o[8];
#pragma unroll
    for (int j = 0; j < 8; j++) {
        int k = k0 + j;
        int c = k & 127, h = k >> 7;
        o[j] = f2b(Wr[(size_t)c * C2 + h * OUTD + n]);
    }
    unsigned short* dst = P + (size_t)fid * 512 + lane * 8;
    *(ushort4*)&dst[0] = *(ushort4*)&o[0];
    *(ushort4*)&dst[4] = *(ushort4*)&o[4];
}

// ---- fused prep (x-cast REMOVED; fused into mfma_gemm): packs | tables | bias ----
#define PACK1_BLOCKS (NREL * (C1/16) * (IND/32) / 4)  // 48
#define PACKV_BLOCKS (NREL * 4 * 16 / 4)              // 48
#define VLR_BLOCKS 6                                  // 3*4*128 threads
#define PREP_BLOCKS (PACK1_BLOCKS + PACKV_BLOCKS + VLR_BLOCKS + 1)
__global__ void prep_kernel(const float* __restrict__ W1, unsigned short* __restrict__ P1,
                            const float* __restrict__ W2, unsigned short* __restrict__ PV,
                            const float* __restrict__ al2, const float* __restrict__ ar2,
                            const float* __restrict__ bb2,
                            float* __restrict__ tabs, float* __restrict__ biasout) {
    int b = blockIdx.x;
    if (b < PACK1_BLOCKS) {
        pack_w_dev<IND, C1>(W1, P1, b * 256 + threadIdx.x);
    } else if (b < PACK1_BLOCKS + PACKV_BLOCKS) {
        pack_v_dev(W2, PV, (b - PACK1_BLOCKS) * 256 + threadIdx.x);
    } else if (b < PACK1_BLOCKS + PACKV_BLOCKS + VLR_BLOCKS) {
        // tabs[j][c], j = (r*4+h)*2 + {0:el,1:er}: vl[r,h,c] = sum_d W2[r][c][h*64+d]*a{l,r}2[r,h,d]
        int t = (b - PACK1_BLOCKS - PACKV_BLOCKS) * 256 + threadIdx.x;
        if (t < NREL * NHEADS * C1) {
            int c = t & 127, rh = t >> 7;
            const float* Wr = W2 + (size_t)(rh >> 2) * C1 * C2 + (size_t)c * C2 + (rh & 3) * OUTD;
            const float* alp = al2 + (size_t)rh * OUTD;
            const float* arp = ar2 + (size_t)rh * OUTD;
            float sl = 0.f, sr = 0.f;
#pragma unroll 4
            for (int d = 0; d < OUTD; d++) {
                sl = fmaf(Wr[d], alp[d], sl);
                sr = fmaf(Wr[d], arp[d], sr);
            }
            tabs[(rh * 2 + 0) * C1 + c] = sl;
            tabs[(rh * 2 + 1) * C1 + c] = sr;
        }
    } else {
        // biasout[nn] = 0.25 * sum_{r,h} b2[r][h*64+nn]
        int t = threadIdx.x;
        if (t < OUTD) {
            float s = 0.f;
#pragma unroll
            for (int rh = 0; rh < NREL * NHEADS; rh++)
                s += bb2[(size_t)(rh >> 2) * C2 + (rh & 3) * OUTD + t];
            biasout[t] = 0.25f * s;
        }
    }
}

// ---- MFMA GEMM + fused coeff, one (relation, 64-row tile) per block ----
// A is FP32 (raw x), converted to bf16 in-kernel at frag-load time (identical RNE
// bits to the old standalone cast pass -> numerics unchanged; 184 MB pass deleted).
template<int K, int N>
__global__ __launch_bounds__(256) void mfma_gemm(
    const float* __restrict__ Ax, const unsigned short* __restrict__ Bp,
    const float* __restrict__ al, const float* __restrict__ ar,
    unsigned short* __restrict__ Zh, float* __restrict__ el, float* __restrict__ er)
{
    const int KS = K / 32, NT = N / 16, MT = 64, NP = N + 4;
    const int wave = threadIdx.x >> 6, lane = threadIdx.x & 63;
    const int r  = blockIdx.y;
    const int m0 = blockIdx.x * MT;
    const int fcol = lane & 15, quad = lane >> 4;

    __shared__ unsigned short zs[MT * (N + 4)];

    int m = m0 + wave * 16 + fcol;
    if (m >= NNODES) m = NNODES - 1;           // clamp; padded rows never consumed
    bf16x8 afrag[KS];
    const float* arowp = Ax + (size_t)m * K + quad * 8;
#pragma unroll
    for (int ks = 0; ks < KS; ks++) {
        float4 fa = *(const float4*)(arowp + ks * 32);
        float4 fb = *(const float4*)(arowp + ks * 32 + 4);
        unsigned short t[8] = { f2b(fa.x), f2b(fa.y), f2b(fa.z), f2b(fa.w),
                                f2b(fb.x), f2b(fb.y), f2b(fb.z), f2b(fb.w) };
        afrag[ks] = *(const bf16x8*)t;
    }

    f32x4 acc[NT];
#pragma unroll
    for (int nt = 0; nt < NT; nt++) { f32x4 z = {0.f,0.f,0.f,0.f}; acc[nt] = z; }

    const unsigned short* Bpr = Bp + (size_t)r * NT * KS * 512;
    for (int ks = 0; ks < KS; ks++) {
        bf16x8 b[NT];
#pragma unroll
        for (int nt = 0; nt < NT; nt++)
            b[nt] = *(const bf16x8*)(Bpr + ((size_t)nt * KS + ks) * 512 + lane * 8);
#pragma unroll
        for (int nt = 0; nt < NT; nt++)
            acc[nt] = __builtin_amdgcn_mfma_f32_16x16x32_bf16(afrag[ks], b[nt], acc[nt], 0, 0, 0);
    }

    {
        int lrow = wave * 16 + quad * 4;
#pragma unroll
        for (int nt = 0; nt < NT; nt++)
#pragma unroll
            for (int q = 0; q < 4; q++)
                zs[(lrow + q) * NP + nt * 16 + fcol] = f2b(acc[nt][q]);
    }
    __syncthreads();

    {
        uint2* zo = (uint2*)(Zh + ((size_t)r * MPAD + m0) * N);
        for (int i = threadIdx.x; i < MT * N / 4; i += 256) {
            int row = i / (N / 4), c4 = i % (N / 4);
            zo[i] = *(const uint2*)&zs[row * NP + c4 * 4];
        }
    }
    {
        const int D = N / NHEADS;
        int row = threadIdx.x >> 2, h = threadIdx.x & 3;
        int n = m0 + row;
        if (n < NNODES) {
            const float* alp = al + ((size_t)r * NHEADS + h) * D;
            const float* arp = ar + ((size_t)r * NHEADS + h) * D;
            const unsigned short* zp = zs + row * NP + h * D;
            float sl = 0.f, sr = 0.f;
#pragma unroll
            for (int d0 = 0; d0 < D; d0 += 4) {
                uint2 u = *(const uint2*)&zp[d0];
                float z0 = b2f((unsigned short)(u.x & 0xffff));
                float z1 = b2f((unsigned short)(u.x >> 16));
                float z2 = b2f((unsigned short)(u.y & 0xffff));
                float z3 = b2f((unsigned short)(u.y >> 16));
                sl = fmaf(z0, alp[d0], sl);     sr = fmaf(z0, arp[d0], sr);
                sl = fmaf(z1, alp[d0 + 1], sl); sr = fmaf(z1, arp[d0 + 1], sr);
                sl = fmaf(z2, alp[d0 + 2], sl); sr = fmaf(z2, arp[d0 + 2], sr);
                sl = fmaf(z3, alp[d0 + 3], sl); sr = fmaf(z3, arp[d0 + 3], sr);
            }
            el[((size_t)r * NNODES + n) * NHEADS + h] = sl;
            er[((size_t)r * NNODES + n) * NHEADS + h] = sr;
        }
    }
}

// ---- build dst-bucketed adjacency ----
__global__ void bucket_fill(const int* __restrict__ src, const int* __restrict__ dst,
                            unsigned* __restrict__ cnt, int* __restrict__ buck) {
    int gid = blockIdx.x * blockDim.x + threadIdx.x;
    if (gid >= NREL * NEDGES) return;
    int r = gid / NEDGES;
    int d = dst[gid];
    int base = r * NNODES + d;
    unsigned pos = atomicAdd(&cnt[base], 1u);
    if (pos < CAP) buck[(size_t)base * CAP + pos] = src[gid];
}

// ---- fused layer-1 aggregate + relu/bias + LAYER-2 LOGITS (elr2 folded in) ----
// one wave per node; lane owns channels 2*lane, 2*lane+1 of C1=128.
// Softmax: no max-subtraction; DPP denominator (no DS ops). Edge loop: ALL lanes
// hold a valid (clamped) source id; inactive lanes publish EXACT-zero alphas, so
// the loop runs a fixed ceil(c/8)*8 slots with 8 loads in flight, no remainder.
__global__ __launch_bounds__(256) void gat_gather1(
    const unsigned* __restrict__ cnt, const int* __restrict__ buck,
    const float* __restrict__ el, const float* __restrict__ er,
    const unsigned short* __restrict__ Zh, const float* __restrict__ b1,
    const float* __restrict__ tabs,
    unsigned short* __restrict__ hbh, float* __restrict__ el2, float* __restrict__ er2)
{
    __shared__ float atab[4][4 * 65];    // per-wave alpha table, stride 65 (bank-spread)
    int wave = threadIdx.x >> 6, lane = threadIdx.x & 63;
    int n = blockIdx.x * 4 + wave;       // grid 7500 * 4 waves = 30000 exact
    const int h0 = lane >> 4;            // head of channels 2*lane..2*lane+1 (D=32)
    f32x2 acc2 = {0.f, 0.f};
    for (int r = 0; r < NREL; r++) {
        int base = r * NNODES + n;
        int c = (int)cnt[base]; c = c < CAP ? c : CAP;
        if (c == 0) continue;
        // clamped read: every lane holds a VALID source id (dups beyond c)
        int s_all = buck[(size_t)base * CAP + (lane < c ? lane : c - 1)];
        float lg[4];
        if (lane < c) {
            const float4 e4 = *(const float4*)&el[((size_t)r * NNODES + s_all) * NHEADS];
            const float4 r4 = *(const float4*)&er[(size_t)base * NHEADS];
            float v;
            v = e4.x + r4.x; lg[0] = v > 0.f ? v : NEG_SLOPE * v;
            v = e4.y + r4.y; lg[1] = v > 0.f ? v : NEG_SLOPE * v;
            v = e4.z + r4.z; lg[2] = v > 0.f ? v : NEG_SLOPE * v;
            v = e4.w + r4.w; lg[3] = v > 0.f ? v : NEG_SLOPE * v;
        } else {
            lg[0] = lg[1] = lg[2] = lg[3] = -INFINITY;   // exp -> exact 0 alpha
        }
#pragma unroll
        for (int h = 0; h < 4; h++) {
            float w = __expf(lg[h]);               // exp(-inf) = 0 for inactive lanes
            float rinv = wave_rcp_sum(w);          // wave-uniform 1/denominator
            atab[wave][h * 65 + lane] = w * rinv;  // wave-private; no barrier needed
        }
        const unsigned short* Zr = Zh + (size_t)r * MPAD * C1;
        const float* at = atab[wave] + h0 * 65;
#define EDGE1A(uu, aa)                                                          \
        {   f32x2 zv = { __uint_as_float((uu) << 16),                           \
                         __uint_as_float((uu) & 0xffff0000u) };                 \
            acc2 = __builtin_elementwise_fma((f32x2){(aa), (aa)}, zv, acc2); }
        int cc = (c + 7) & ~7;                     // padded slots: alpha == 0 exactly
        for (int j = 0; j < cc; j += 8) {
            int ss[8];
#pragma unroll
            for (int q = 0; q < 8; q++) ss[q] = __builtin_amdgcn_readlane(s_all, j + q);
            unsigned zz[8];
#pragma unroll
            for (int q = 0; q < 8; q++)
                zz[q] = *(const unsigned*)&Zr[(size_t)ss[q] * C1 + 2 * lane];
#pragma unroll
            for (int q = 0; q < 8; q++) { float a0 = at[j + q]; EDGE1A(zz[q], a0); }
        }
#undef EDGE1A
    }
    int cch = 2 * lane;
    float bx = b1[cch]     + b1[C1 + cch]     + b1[2 * C1 + cch];
    float by = b1[cch + 1] + b1[C1 + cch + 1] + b1[2 * C1 + cch + 1];
    ushort2 o;
    o.x = f2b(fmaxf(acc2.x + bx, 0.f));
    o.y = f2b(fmaxf(acc2.y + by, 0.f));
    *(ushort2*)&hbh[(size_t)n * C1 + cch] = o;

    // ---- folded elr2: layer-2 logits from the bf16-rounded h1, DPP reduction ----
    float hx = b2f(o.x), hy = b2f(o.y);
    for (int half = 0; half < 2; half++) {       // 2 passes of 12 caps VGPR pressure
        float p[12];
#pragma unroll
        for (int j = 0; j < 12; j++) {
            const float2 t = *(const float2*)&tabs[(half * 12 + j) * C1 + cch];
            p[j] = fmaf(hy, t.y, hx * t.x);
        }
#pragma unroll
        for (int j = 0; j < 12; j++) p[j] = dpp_wsum63(p[j]);
        if (lane == 63) {
#pragma unroll
            for (int j = 0; j < 12; j++) {
                int jj = half * 12 + j;
                int rh = jj >> 1;
                size_t idx = ((size_t)(rh >> 2) * NNODES + n) * NHEADS + (rh & 3);
                if (jj & 1) er2[idx] = p[j]; else el2[idx] = p[j];
            }
        }
    }
}

// ---- fused layer-2: edge softmax + per-head h1 aggregation + MFMA (agg@V) ----
// block = 512 threads = 8 waves, ONE NODE PER WAVE (30000 gather waves, grid 3750).
// 32 KB LDS -> 4 blocks/CU. DPP softmax; fixed-count 8-deep pipelined edge loop
// (padded slots have exact-zero alpha). One barrier, then waves 0-3 do the
// (8x1536)@(1536x64) MFMA (A rows 8-15 alias 0-7).
__global__ __launch_bounds__(512, 8) void gat_gather2f(
    const unsigned* __restrict__ cnt, const int* __restrict__ buck,
    const float* __restrict__ el, const float* __restrict__ er,
    const unsigned short* __restrict__ hbh, const unsigned short* __restrict__ PV,
    const float* __restrict__ biasout, float* __restrict__ out)
{
    __shared__ unsigned short aggs[8 * 1536];      // 24 KB, row stride 3072 B, XOR-swizzled
    __shared__ float atv[8][64 * 4];               // 8 KB: per-wave alpha float4 per edge
    const int wave = threadIdx.x >> 6, lane = threadIdx.x & 63;
    const int fcol = lane & 15, quad = lane >> 4;
    const int n0 = blockIdx.x * 8;                 // 30000/8 = 3750 exact
    const int n  = n0 + wave;                      // this wave's node

    for (int r = 0; r < NREL; r++) {
        f32x2 ag[4];                               // [h]: lane owns h1 ch {2l, 2l+1}
#pragma unroll
        for (int k = 0; k < 4; k++) ag[k] = (f32x2){0.f, 0.f};

        int base = r * NNODES + n;
        int c = (int)cnt[base]; c = c < CAP ? c : CAP;
        if (c > 0) {
            int s_all = buck[(size_t)base * CAP + (lane < c ? lane : c - 1)];
            float lg[4];
            if (lane < c) {
                const float4 e4 = *(const float4*)&el[((size_t)r * NNODES + s_all) * NHEADS];
                const float4 r4 = *(const float4*)&er[(size_t)base * NHEADS];
                float v;
                v = e4.x + r4.x; lg[0] = v > 0.f ? v : NEG_SLOPE * v;
                v = e4.y + r4.y; lg[1] = v > 0.f ? v : NEG_SLOPE * v;
                v = e4.z + r4.z; lg[2] = v > 0.f ? v : NEG_SLOPE * v;
                v = e4.w + r4.w; lg[3] = v > 0.f ? v : NEG_SLOPE * v;
            } else {
                lg[0] = lg[1] = lg[2] = lg[3] = -INFINITY;
            }
            float aw[4];
#pragma unroll
            for (int h = 0; h < 4; h++) {
                float w = __expf(lg[h]);               // exp(-inf)=0 for inactive lanes
                aw[h] = w * wave_rcp_sum(w);           // exact 0 beyond c
            }
            // lane j publishes all 4 alphas of edge j as one float4 (wave-private)
            float4 aq = { aw[0], aw[1], aw[2], aw[3] };
            *(float4*)&atv[wave][lane * 4] = aq;
            const float4* at = (const float4*)&atv[wave][0];

#define EDGE1(zz, aa)                                                             \
            {   f32x2 zv = { __uint_as_float((zz) << 16),                         \
                             __uint_as_float((zz) & 0xffff0000u) };               \
                ag[0] = __builtin_elementwise_fma((f32x2){(aa).x,(aa).x}, zv, ag[0]); \
                ag[1] = __builtin_elementwise_fma((f32x2){(aa).y,(aa).y}, zv, ag[1]); \
                ag[2] = __builtin_elementwise_fma((f32x2){(aa).z,(aa).z}, zv, ag[2]); \
                ag[3] = __builtin_elementwise_fma((f32x2){(aa).w,(aa).w}, zv, ag[3]); }
            int cc = (c + 7) & ~7;                 // padded slots: alpha == 0 exactly
            for (int j = 0; j < cc; j += 8) {
                int ss[8];
#pragma unroll
                for (int q = 0; q < 8; q++) ss[q] = __builtin_amdgcn_readlane(s_all, j + q);
                unsigned zz[8];
#pragma unroll
                for (int q = 0; q < 8; q++)
                    zz[q] = *(const unsigned*)&hbh[(size_t)ss[q] * C1 + 2 * lane];
#pragma unroll
                for (int q = 0; q < 8; q++) { float4 a0 = at[j + q]; EDGE1(zz[q], a0); }
            }
#undef EDGE1
        }

        // dump this wave's row chunk (zeros if c==0): ushort col = h*128 + 2*lane,
        // byte = r*1024 + (h*256 + lane*4) ^ (wave<<4)   [XOR bits 4-6; row = wave < 8]
        {
            unsigned sw = (unsigned)(wave << 4);
            char* basep = (char*)aggs + wave * 3072 + r * 1024;
#pragma unroll
            for (int h = 0; h < 4; h++) {
                unsigned pk = ((unsigned)f2b(ag[h].y) << 16) | f2b(ag[h].x);
                *(unsigned*)(basep + (((unsigned)(h * 256 + lane * 4)) ^ sw)) = pk;
            }
        }
    }

    __syncthreads();

    // MFMA: wave w < 4 computes out cols [16w, 16w+16) over K = 1536 (3 rels concat)
    if (wave < 4) {
        f32x4 acc = {0.f, 0.f, 0.f, 0.f};
        const int arow = fcol & 7;                 // rows 8-15 alias rows 0-7
        for (int rr = 0; rr < NREL; rr++) {
            const unsigned short* PVr = PV + ((size_t)(rr * 4 + wave) * 16) * 512;
#pragma unroll
            for (int ks = 0; ks < 16; ks++) {
                bf16x8 b = *(const bf16x8*)(PVr + (size_t)ks * 512 + lane * 8);
                const char* ap = (const char*)aggs + arow * 3072 +
                                 (((unsigned)(rr * 1024 + ks * 64 + quad * 16)) ^
                                  ((unsigned)(arow << 4)));
                bf16x8 a = *(const bf16x8*)ap;
                acc = __builtin_amdgcn_mfma_f32_16x16x32_bf16(a, b, acc, 0, 0, 0);
            }
        }
        // epilogue: D rows 0-7 only (quad 0,1). out = 0.25*acc + biasout
        if (quad < 2) {
            int col = wave * 16 + fcol;
            float bias = biasout[col];
#pragma unroll
            for (int q = 0; q < 4; q++) {
                int row = n0 + quad * 4 + q;
                out[(size_t)row * OUTD + col] = fmaf(0.25f, acc[q], bias);
            }
        }
    }
}

extern "C" void kernel_launch(void* const* d_in, const int* in_sizes, int n_in,
                              void* d_out, int out_size, void* d_ws, size_t ws_size,
                              hipStream_t stream) {
    (void)in_sizes; (void)n_in; (void)out_size; (void)ws_size;
    const float* x   = (const float*)d_in[0];
    const int*   src = (const int*)d_in[1];
    const int*   dst = (const int*)d_in[2];
    const float* W1  = (const float*)d_in[3];
    const float* al1 = (const float*)d_in[4];
    const float* ar1 = (const float*)d_in[5];
    const float* b1  = (const float*)d_in[6];
    const float* W2  = (const float*)d_in[7];
    const float* al2 = (const float*)d_in[8];
    const float* ar2 = (const float*)d_in[9];
    const float* b2  = (const float*)d_in[10];
    float* out = (float*)d_out;

    // ---- workspace layout (float-offset based; every chunk 16B-aligned) ----
    float* ws = (float*)d_ws;
    size_t off = 0;
    unsigned short* Zh  = (unsigned short*)(ws + off); off += (size_t)NREL * MPAD * C1 / 2;
    unsigned short* hbh = (unsigned short*)(ws + off); off += (size_t)NNODES * C1 / 2;
    unsigned short* P1  = (unsigned short*)(ws + off); off += (size_t)NREL * (C1/16) * (IND/32) * 512 / 2;
    unsigned short* PV  = (unsigned short*)(ws + off); off += (size_t)NREL * 4 * 16 * 512 / 2;
    float* el  = ws + off; off += (size_t)NREL * NNODES * NHEADS;
    float* er  = ws + off; off += (size_t)NREL * NNODES * NHEADS;
    float* el2 = ws + off; off += (size_t)NREL * NNODES * NHEADS;
    float* er2 = ws + off; off += (size_t)NREL * NNODES * NHEADS;
    unsigned* cnt = (unsigned*)(ws + off); off += (size_t)NREL * NNODES;
    int* buck  = (int*)(ws + off); off += (size_t)NREL * NNODES * CAP;
    float* tabs    = ws + off; off += 24 * C1;     // layer-2 attn projection tables
    float* biasout = ws + off; off += OUTD;        // 0.25 * sum_{r,h} b2

    const int TB = 256;

    // ---- adjacency build + pack/proj prep (x-cast fused into mfma_gemm) ----
    hipMemsetAsync(cnt, 0, (size_t)NREL * NNODES * sizeof(unsigned), stream);
    bucket_fill<<<(NREL * NEDGES + TB - 1) / TB, TB, 0, stream>>>(src, dst, cnt, buck);
    prep_kernel<<<PREP_BLOCKS, TB, 0, stream>>>(W1, P1, W2, PV, al2, ar2, b2,
                                                tabs, biasout);

    // ================= layer 1 (+ folded layer-2 logits) =================
    {
        dim3 grid(MPAD / 64, NREL);
        mfma_gemm<IND, C1><<<grid, 256, 0, stream>>>(x, P1, al1, ar1, Zh, el, er);
    }
    gat_gather1<<<NNODES / 4, 256, 0, stream>>>(cnt, buck, el, er, Zh, b1, tabs,
                                                hbh, el2, er2);

    // ================= layer 2 (no z2 GEMM: aggregate-then-multiply) =================
    gat_gather2f<<<NNODES / 8, 512, 0, stream>>>(cnt, buck, el2, er2, hbh, PV, biasout, out);
}

// Round 9
// 301.059 us; speedup vs baseline: 1.0353x; 1.0353x over previous
//
#include <hip/hip_runtime.h>
#include <math.h>

#define NNODES 30000
#define MPAD   30080          // padded Z row count per relation (470*64)
#define NEDGES 300000
#define NREL 3
#define IND 256
#define HIDD 32
#define OUTD 64
#define NHEADS 4
#define C1 (NHEADS*HIDD)    // 128
#define C2 (NHEADS*OUTD)    // 256
#define NEG_SLOPE 0.2f
#define CAP 64              // max in-degree per (rel,node); Poisson(10) -> P(>=64) ~ 1e-30

typedef short bf16x8 __attribute__((ext_vector_type(8)));
typedef float f32x4  __attribute__((ext_vector_type(4)));
typedef float f32x2  __attribute__((ext_vector_type(2)));

// ---- bf16 <-> f32 helpers (RNE pack; exact unpack) ----
__device__ __forceinline__ float b2f(unsigned short u) {
    return __uint_as_float(((unsigned)u) << 16);
}
__device__ __forceinline__ unsigned short f2b(float f) {
    unsigned u = __float_as_uint(f);
    u += 0x7fffu + ((u >> 16) & 1u);     // round-to-nearest-even
    return (unsigned short)(u >> 16);
}

// ---- DPP wave64 sum: VALU-pipe reduction (NO ds_swizzle -> no LDS-unit pressure) ----
template<int CTRL>
__device__ __forceinline__ float dppadd(float x) {
    int s = __builtin_amdgcn_update_dpp(0, __float_as_int(x), CTRL, 0xf, 0xf, true);
    return x + __int_as_float(s);
}
__device__ __forceinline__ float dpp_wsum63(float x) {
    x = dppadd<0x111>(x);    // row_shr:1
    x = dppadd<0x112>(x);    // row_shr:2
    x = dppadd<0x114>(x);    // row_shr:4
    x = dppadd<0x118>(x);    // row_shr:8  -> lane15/31/47/63 hold row sums
    x = dppadd<0x142>(x);    // row_bcast15 -> lane31/63 hold half sums
    x = dppadd<0x143>(x);    // row_bcast31 -> lane63 holds full sum
    return x;
}
// wave-uniform 1/sum (rcp is 1-ulp; denominator is a sum of positives)
__device__ __forceinline__ float wave_rcp_sum(float w) {
    float den = __uint_as_float(__builtin_amdgcn_readlane(
        __float_as_uint(dpp_wsum63(w)), 63));
    return __builtin_amdgcn_rcpf(den);
}

// ---- pack W[r] (row-major KxN fp32) into MFMA B-fragment order, bf16 ----
template<int K, int N>
__device__ __forceinline__ void pack_w_dev(const float* __restrict__ W,
                                           unsigned short* __restrict__ P, int t) {
    const int KS = K / 32, NT = N / 16;
    int lane = t & 63;
    int fid = t >> 6;
    if (fid >= NREL * NT * KS) return;
    int ks = fid % KS;
    int nt = (fid / KS) % NT;
    int r  = fid / (KS * NT);
    int n  = nt * 16 + (lane & 15);
    int k0 = ks * 32 + (lane >> 4) * 8;
    const float* Wr = W + (size_t)r * K * N;
    unsigned short o[8];
#pragma unroll
    for (int j = 0; j < 8; j++) o[j] = f2b(Wr[(size_t)(k0 + j) * N + n]);
    unsigned short* dst = P + (size_t)fid * 512 + lane * 8;
    *(ushort4*)&dst[0] = *(ushort4*)&o[0];
    *(ushort4*)&dst[4] = *(ushort4*)&o[4];
}

// ---- pack V[r] (K=512 x N=64) B-frags, V[r][h*128+c][n] = W2[r][c][h*64+n] ----
__device__ __forceinline__ void pack_v_dev(const float* __restrict__ W2,
                                           unsigned short* __restrict__ P, int t) {
    const int KS = 16, NT = 4;   // K=512, N=64
    int lane = t & 63;
    int fid = t >> 6;
    if (fid >= NREL * NT * KS) return;
    int ks = fid % KS;
    int nt = (fid / KS) % NT;
    int r  = fid / (KS * NT);
    int n  = nt * 16 + (lane & 15);
    int k0 = ks * 32 + (lane >> 4) * 8;
    const float* Wr = W2 + (size_t)r * C1 * C2;
    unsigned short o[8];
#pragma unroll
    for (int j = 0; j < 8; j++) {
        int k = k0 + j;
        int c = k & 127, h = k >> 7;
        o[j] = f2b(Wr[(size_t)c * C2 + h * OUTD + n]);
    }
    unsigned short* dst = P + (size_t)fid * 512 + lane * 8;
    *(ushort4*)&dst[0] = *(ushort4*)&o[0];
    *(ushort4*)&dst[4] = *(ushort4*)&o[4];
}

// ---- fused prep: bucket_fill | pack W1 | pack V | attn-proj tables | bias ----
// bucket_fill merged in (independent work, saves a dispatch + overlaps).
#define BF_BLOCKS ((NREL * NEDGES + 255) / 256)       // 3516
#define PACK1_BLOCKS (NREL * (C1/16) * (IND/32) / 4)  // 48
#define PACKV_BLOCKS (NREL * 4 * 16 / 4)              // 48
#define VLR_BLOCKS 6                                  // 3*4*128 threads
#define PREP_BLOCKS (BF_BLOCKS + PACK1_BLOCKS + PACKV_BLOCKS + VLR_BLOCKS + 1)
__global__ void prep_kernel(const int* __restrict__ src, const int* __restrict__ dst,
                            unsigned* __restrict__ cnt, int* __restrict__ buck,
                            const float* __restrict__ W1, unsigned short* __restrict__ P1,
                            const float* __restrict__ W2, unsigned short* __restrict__ PV,
                            const float* __restrict__ al2, const float* __restrict__ ar2,
                            const float* __restrict__ bb2,
                            float* __restrict__ tabs, float* __restrict__ biasout) {
    int b = blockIdx.x;
    if (b < BF_BLOCKS) {
        int gid = b * 256 + threadIdx.x;
        if (gid >= NREL * NEDGES) return;
        int r = gid / NEDGES;
        int d = dst[gid];
        int base = r * NNODES + d;
        unsigned pos = atomicAdd(&cnt[base], 1u);
        if (pos < CAP) buck[(size_t)base * CAP + pos] = src[gid];
    } else if (b < BF_BLOCKS + PACK1_BLOCKS) {
        pack_w_dev<IND, C1>(W1, P1, (b - BF_BLOCKS) * 256 + threadIdx.x);
    } else if (b < BF_BLOCKS + PACK1_BLOCKS + PACKV_BLOCKS) {
        pack_v_dev(W2, PV, (b - BF_BLOCKS - PACK1_BLOCKS) * 256 + threadIdx.x);
    } else if (b < BF_BLOCKS + PACK1_BLOCKS + PACKV_BLOCKS + VLR_BLOCKS) {
        // tabs[j][c], j = (r*4+h)*2 + {0:el,1:er}: vl[r,h,c] = sum_d W2[r][c][h*64+d]*a{l,r}2[r,h,d]
        int t = (b - BF_BLOCKS - PACK1_BLOCKS - PACKV_BLOCKS) * 256 + threadIdx.x;
        if (t < NREL * NHEADS * C1) {
            int c = t & 127, rh = t >> 7;
            const float* Wr = W2 + (size_t)(rh >> 2) * C1 * C2 + (size_t)c * C2 + (rh & 3) * OUTD;
            const float* alp = al2 + (size_t)rh * OUTD;
            const float* arp = ar2 + (size_t)rh * OUTD;
            float sl = 0.f, sr = 0.f;
#pragma unroll 4
            for (int d = 0; d < OUTD; d++) {
                sl = fmaf(Wr[d], alp[d], sl);
                sr = fmaf(Wr[d], arp[d], sr);
            }
            tabs[(rh * 2 + 0) * C1 + c] = sl;
            tabs[(rh * 2 + 1) * C1 + c] = sr;
        }
    } else {
        // biasout[nn] = 0.25 * sum_{r,h} b2[r][h*64+nn]
        int t = threadIdx.x;
        if (t < OUTD) {
            float s = 0.f;
#pragma unroll
            for (int rh = 0; rh < NREL * NHEADS; rh++)
                s += bb2[(size_t)(rh >> 2) * C2 + (rh & 3) * OUTD + t];
            biasout[t] = 0.25f * s;
        }
    }
}

// ---- MFMA GEMM + fused coeff, one (relation, 64-row tile) per block ----
// A is FP32 (raw x), converted to bf16 in-kernel at frag-load time (RNE bits
// identical to a standalone cast pass -> numerics unchanged).
template<int K, int N>
__global__ __launch_bounds__(256) void mfma_gemm(
    const float* __restrict__ Ax, const unsigned short* __restrict__ Bp,
    const float* __restrict__ al, const float* __restrict__ ar,
    unsigned short* __restrict__ Zh, float* __restrict__ el, float* __restrict__ er)
{
    const int KS = K / 32, NT = N / 16, MT = 64, NP = N + 4;
    const int wave = threadIdx.x >> 6, lane = threadIdx.x & 63;
    const int r  = blockIdx.y;
    const int m0 = blockIdx.x * MT;
    const int fcol = lane & 15, quad = lane >> 4;

    __shared__ unsigned short zs[MT * (N + 4)];

    int m = m0 + wave * 16 + fcol;
    if (m >= NNODES) m = NNODES - 1;           // clamp; padded rows never consumed
    bf16x8 afrag[KS];
    const float* arowp = Ax + (size_t)m * K + quad * 8;
#pragma unroll
    for (int ks = 0; ks < KS; ks++) {
        float4 fa = *(const float4*)(arowp + ks * 32);
        float4 fb = *(const float4*)(arowp + ks * 32 + 4);
        unsigned short t[8] = { f2b(fa.x), f2b(fa.y), f2b(fa.z), f2b(fa.w),
                                f2b(fb.x), f2b(fb.y), f2b(fb.z), f2b(fb.w) };
        afrag[ks] = *(const bf16x8*)t;
    }

    f32x4 acc[NT];
#pragma unroll
    for (int nt = 0; nt < NT; nt++) { f32x4 z = {0.f,0.f,0.f,0.f}; acc[nt] = z; }

    const unsigned short* Bpr = Bp + (size_t)r * NT * KS * 512;
    for (int ks = 0; ks < KS; ks++) {
        bf16x8 b[NT];
#pragma unroll
        for (int nt = 0; nt < NT; nt++)
            b[nt] = *(const bf16x8*)(Bpr + ((size_t)nt * KS + ks) * 512 + lane * 8);
#pragma unroll
        for (int nt = 0; nt < NT; nt++)
            acc[nt] = __builtin_amdgcn_mfma_f32_16x16x32_bf16(afrag[ks], b[nt], acc[nt], 0, 0, 0);
    }

    {
        int lrow = wave * 16 + quad * 4;
#pragma unroll
        for (int nt = 0; nt < NT; nt++)
#pragma unroll
            for (int q = 0; q < 4; q++)
                zs[(lrow + q) * NP + nt * 16 + fcol] = f2b(acc[nt][q]);
    }
    __syncthreads();

    {
        uint2* zo = (uint2*)(Zh + ((size_t)r * MPAD + m0) * N);
        for (int i = threadIdx.x; i < MT * N / 4; i += 256) {
            int row = i / (N / 4), c4 = i % (N / 4);
            zo[i] = *(const uint2*)&zs[row * NP + c4 * 4];
        }
    }
    {
        const int D = N / NHEADS;
        int row = threadIdx.x >> 2, h = threadIdx.x & 3;
        int n = m0 + row;
        if (n < NNODES) {
            const float* alp = al + ((size_t)r * NHEADS + h) * D;
            const float* arp = ar + ((size_t)r * NHEADS + h) * D;
            const unsigned short* zp = zs + row * NP + h * D;
            float sl = 0.f, sr = 0.f;
#pragma unroll
            for (int d0 = 0; d0 < D; d0 += 4) {
                uint2 u = *(const uint2*)&zp[d0];
                float z0 = b2f((unsigned short)(u.x & 0xffff));
                float z1 = b2f((unsigned short)(u.x >> 16));
                float z2 = b2f((unsigned short)(u.y & 0xffff));
                float z3 = b2f((unsigned short)(u.y >> 16));
                sl = fmaf(z0, alp[d0], sl);     sr = fmaf(z0, arp[d0], sr);
                sl = fmaf(z1, alp[d0 + 1], sl); sr = fmaf(z1, arp[d0 + 1], sr);
                sl = fmaf(z2, alp[d0 + 2], sl); sr = fmaf(z2, arp[d0 + 2], sr);
                sl = fmaf(z3, alp[d0 + 3], sl); sr = fmaf(z3, arp[d0 + 3], sr);
            }
            el[((size_t)r * NNODES + n) * NHEADS + h] = sl;
            er[((size_t)r * NNODES + n) * NHEADS + h] = sr;
        }
    }
}

// ---- fused layer-1 aggregate + relu/bias + LAYER-2 LOGITS (elr2 folded in) ----
// one wave per node; lane owns channels 2*lane, 2*lane+1 of C1=128 (one head).
// Edge loop: scalar fmaf accumulators (2 v_fmac/edge; NO f32x2 broadcast-builds).
__global__ __launch_bounds__(256) void gat_gather1(
    const unsigned* __restrict__ cnt, const int* __restrict__ buck,
    const float* __restrict__ el, const float* __restrict__ er,
    const unsigned short* __restrict__ Zh, const float* __restrict__ b1,
    const float* __restrict__ tabs,
    unsigned short* __restrict__ hbh, float* __restrict__ el2, float* __restrict__ er2)
{
    __shared__ float atab[4][4 * 65];    // per-wave alpha table, stride 65 (bank-spread)
    int wave = threadIdx.x >> 6, lane = threadIdx.x & 63;
    int n = blockIdx.x * 4 + wave;       // grid 7500 * 4 waves = 30000 exact
    const int h0 = lane >> 4;            // head of channels 2*lane..2*lane+1 (D=32)
    float accx = 0.f, accy = 0.f;
    for (int r = 0; r < NREL; r++) {
        int base = r * NNODES + n;
        int c = (int)cnt[base]; c = c < CAP ? c : CAP;
        if (c == 0) continue;
        // clamped read: every lane holds a VALID source id (dups beyond c)
        int s_all = buck[(size_t)base * CAP + (lane < c ? lane : c - 1)];
        float lg[4];
        if (lane < c) {
            const float4 e4 = *(const float4*)&el[((size_t)r * NNODES + s_all) * NHEADS];
            const float4 r4 = *(const float4*)&er[(size_t)base * NHEADS];
            float v;
            v = e4.x + r4.x; lg[0] = v > 0.f ? v : NEG_SLOPE * v;
            v = e4.y + r4.y; lg[1] = v > 0.f ? v : NEG_SLOPE * v;
            v = e4.z + r4.z; lg[2] = v > 0.f ? v : NEG_SLOPE * v;
            v = e4.w + r4.w; lg[3] = v > 0.f ? v : NEG_SLOPE * v;
        } else {
            lg[0] = lg[1] = lg[2] = lg[3] = -INFINITY;   // exp -> exact 0 alpha
        }
#pragma unroll
        for (int h = 0; h < 4; h++) {
            float w = __expf(lg[h]);               // exp(-inf) = 0 for inactive lanes
            float rinv = wave_rcp_sum(w);          // wave-uniform 1/denominator
            atab[wave][h * 65 + lane] = w * rinv;  // wave-private; no barrier needed
        }
        const unsigned short* Zr = Zh + (size_t)r * MPAD * C1;
        const float* at = atab[wave] + h0 * 65;
        int cc = (c + 7) & ~7;                     // padded slots: alpha == 0 exactly
        for (int j = 0; j < cc; j += 8) {
            int ss[8];
#pragma unroll
            for (int q = 0; q < 8; q++) ss[q] = __builtin_amdgcn_readlane(s_all, j + q);
            unsigned zz[8];
#pragma unroll
            for (int q = 0; q < 8; q++)
                zz[q] = *(const unsigned*)&Zr[(size_t)ss[q] * C1 + 2 * lane];
#pragma unroll
            for (int q = 0; q < 8; q++) {
                float a0 = at[j + q];
                float z0 = __uint_as_float(zz[q] << 16);
                float z1 = __uint_as_float(zz[q] & 0xffff0000u);
                accx = fmaf(a0, z0, accx);
                accy = fmaf(a0, z1, accy);
            }
        }
    }
    int cch = 2 * lane;
    float bx = b1[cch]     + b1[C1 + cch]     + b1[2 * C1 + cch];
    float by = b1[cch + 1] + b1[C1 + cch + 1] + b1[2 * C1 + cch + 1];
    ushort2 o;
    o.x = f2b(fmaxf(accx + bx, 0.f));
    o.y = f2b(fmaxf(accy + by, 0.f));
    *(ushort2*)&hbh[(size_t)n * C1 + cch] = o;

    // ---- folded elr2: layer-2 logits from the bf16-rounded h1, DPP reduction ----
    float hx = b2f(o.x), hy = b2f(o.y);
    for (int half = 0; half < 2; half++) {       // 2 passes of 12 caps VGPR pressure
        float p[12];
#pragma unroll
        for (int j = 0; j < 12; j++) {
            const float2 t = *(const float2*)&tabs[(half * 12 + j) * C1 + cch];
            p[j] = fmaf(hy, t.y, hx * t.x);
        }
#pragma unroll
        for (int j = 0; j < 12; j++) p[j] = dpp_wsum63(p[j]);
        if (lane == 63) {
#pragma unroll
            for (int j = 0; j < 12; j++) {
                int jj = half * 12 + j;
                int rh = jj >> 1;
                size_t idx = ((size_t)(rh >> 2) * NNODES + n) * NHEADS + (rh & 3);
                if (jj & 1) er2[idx] = p[j]; else el2[idx] = p[j];
            }
        }
    }
}

// ---- fused layer-2: edge softmax + per-head h1 aggregation + MFMA (agg@V) ----
// block = 512 threads = 8 waves, ONE NODE PER WAVE. Edge loop uses inline-asm
// v_pk_fma_f32 with op_sel broadcast: alpha pairs (a0,a1)/(a2,a3) come straight
// from the LDS float4 (no broadcast v_movs); 4 pk_fma + 2 unpack per edge.
__global__ __launch_bounds__(512, 8) void gat_gather2f(
    const unsigned* __restrict__ cnt, const int* __restrict__ buck,
    const float* __restrict__ el, const float* __restrict__ er,
    const unsigned short* __restrict__ hbh, const unsigned short* __restrict__ PV,
    const float* __restrict__ biasout, float* __restrict__ out)
{
    __shared__ unsigned short aggs[8 * 1536];      // 24 KB, row stride 3072 B, XOR-swizzled
    __shared__ float atv[8][64 * 4];               // 8 KB: per-wave alpha float4 per edge
    const int wave = threadIdx.x >> 6, lane = threadIdx.x & 63;
    const int fcol = lane & 15, quad = lane >> 4;
    const int n0 = blockIdx.x * 8;                 // 30000/8 = 3750 exact
    const int n  = n0 + wave;                      // this wave's node

    for (int r = 0; r < NREL; r++) {
        f32x2 ag0 = {0.f, 0.f}, ag1 = {0.f, 0.f}, ag2 = {0.f, 0.f}, ag3 = {0.f, 0.f};

        int base = r * NNODES + n;
        int c = (int)cnt[base]; c = c < CAP ? c : CAP;
        if (c > 0) {
            int s_all = buck[(size_t)base * CAP + (lane < c ? lane : c - 1)];
            float lg[4];
            if (lane < c) {
                const float4 e4 = *(const float4*)&el[((size_t)r * NNODES + s_all) * NHEADS];
                const float4 r4 = *(const float4*)&er[(size_t)base * NHEADS];
                float v;
                v = e4.x + r4.x; lg[0] = v > 0.f ? v : NEG_SLOPE * v;
                v = e4.y + r4.y; lg[1] = v > 0.f ? v : NEG_SLOPE * v;
                v = e4.z + r4.z; lg[2] = v > 0.f ? v : NEG_SLOPE * v;
                v = e4.w + r4.w; lg[3] = v > 0.f ? v : NEG_SLOPE * v;
            } else {
                lg[0] = lg[1] = lg[2] = lg[3] = -INFINITY;
            }
            float aw[4];
#pragma unroll
            for (int h = 0; h < 4; h++) {
                float w = __expf(lg[h]);               // exp(-inf)=0 for inactive lanes
                aw[h] = w * wave_rcp_sum(w);           // exact 0 beyond c
            }
            // lane j publishes all 4 alphas of edge j as one float4 (wave-private)
            float4 aq = { aw[0], aw[1], aw[2], aw[3] };
            *(float4*)&atv[wave][lane * 4] = aq;
            const float* at4 = &atv[wave][0];

            int cc = (c + 7) & ~7;                 // padded slots: alpha == 0 exactly
            for (int j = 0; j < cc; j += 8) {
                int ss[8];
#pragma unroll
                for (int q = 0; q < 8; q++) ss[q] = __builtin_amdgcn_readlane(s_all, j + q);
                unsigned zz[8];
#pragma unroll
                for (int q = 0; q < 8; q++)
                    zz[q] = *(const unsigned*)&hbh[(size_t)ss[q] * C1 + 2 * lane];
#pragma unroll
                for (int q = 0; q < 8; q++) {
                    f32x4 a4 = *(const f32x4*)&at4[(j + q) * 4];
                    f32x2 a01 = __builtin_shufflevector(a4, a4, 0, 1);
                    f32x2 a23 = __builtin_shufflevector(a4, a4, 2, 3);
                    f32x2 zp;
                    zp.x = __uint_as_float(zz[q] << 16);
                    zp.y = __uint_as_float(zz[q] & 0xffff0000u);
                    // ag_h += a_h * (z0,z1): src0 half selected by op_sel/op_sel_hi
                    asm("v_pk_fma_f32 %0, %1, %2, %0 op_sel:[0,0,0] op_sel_hi:[0,1,1]"
                        : "+v"(ag0) : "v"(a01), "v"(zp));
                    asm("v_pk_fma_f32 %0, %1, %2, %0 op_sel:[1,0,0] op_sel_hi:[1,1,1]"
                        : "+v"(ag1) : "v"(a01), "v"(zp));
                    asm("v_pk_fma_f32 %0, %1, %2, %0 op_sel:[0,0,0] op_sel_hi:[0,1,1]"
                        : "+v"(ag2) : "v"(a23), "v"(zp));
                    asm("v_pk_fma_f32 %0, %1, %2, %0 op_sel:[1,0,0] op_sel_hi:[1,1,1]"
                        : "+v"(ag3) : "v"(a23), "v"(zp));
                }
            }
        }

        // dump this wave's row chunk (zeros if c==0): ushort col = h*128 + 2*lane,
        // byte = r*1024 + (h*256 + lane*4) ^ (wave<<4)   [XOR bits 4-6; row = wave < 8]
        {
            unsigned sw = (unsigned)(wave << 4);
            char* basep = (char*)aggs + wave * 3072 + r * 1024;
            unsigned pk0 = ((unsigned)f2b(ag0.y) << 16) | f2b(ag0.x);
            unsigned pk1 = ((unsigned)f2b(ag1.y) << 16) | f2b(ag1.x);
            unsigned pk2 = ((unsigned)f2b(ag2.y) << 16) | f2b(ag2.x);
            unsigned pk3 = ((unsigned)f2b(ag3.y) << 16) | f2b(ag3.x);
            *(unsigned*)(basep + (((unsigned)(0 * 256 + lane * 4)) ^ sw)) = pk0;
            *(unsigned*)(basep + (((unsigned)(1 * 256 + lane * 4)) ^ sw)) = pk1;
            *(unsigned*)(basep + (((unsigned)(2 * 256 + lane * 4)) ^ sw)) = pk2;
            *(unsigned*)(basep + (((unsigned)(3 * 256 + lane * 4)) ^ sw)) = pk3;
        }
    }

    __syncthreads();

    // MFMA: wave w < 4 computes out cols [16w, 16w+16) over K = 1536 (3 rels concat)
    if (wave < 4) {
        f32x4 acc = {0.f, 0.f, 0.f, 0.f};
        const int arow = fcol & 7;                 // rows 8-15 alias rows 0-7
        for (int rr = 0; rr < NREL; rr++) {
            const unsigned short* PVr = PV + ((size_t)(rr * 4 + wave) * 16) * 512;
#pragma unroll
            for (int ks = 0; ks < 16; ks++) {
                bf16x8 b = *(const bf16x8*)(PVr + (size_t)ks * 512 + lane * 8);
                const char* ap = (const char*)aggs + arow * 3072 +
                                 (((unsigned)(rr * 1024 + ks * 64 + quad * 16)) ^
                                  ((unsigned)(arow << 4)));
                bf16x8 a = *(const bf16x8*)ap;
                acc = __builtin_amdgcn_mfma_f32_16x16x32_bf16(a, b, acc, 0, 0, 0);
            }
        }
        // epilogue: D rows 0-7 only (quad 0,1). out = 0.25*acc + biasout
        if (quad < 2) {
            int col = wave * 16 + fcol;
            float bias = biasout[col];
#pragma unroll
            for (int q = 0; q < 4; q++) {
                int row = n0 + quad * 4 + q;
                out[(size_t)row * OUTD + col] = fmaf(0.25f, acc[q], bias);
            }
        }
    }
}

extern "C" void kernel_launch(void* const* d_in, const int* in_sizes, int n_in,
                              void* d_out, int out_size, void* d_ws, size_t ws_size,
                              hipStream_t stream) {
    (void)in_sizes; (void)n_in; (void)out_size; (void)ws_size;
    const float* x   = (const float*)d_in[0];
    const int*   src = (const int*)d_in[1];
    const int*   dst = (const int*)d_in[2];
    const float* W1  = (const float*)d_in[3];
    const float* al1 = (const float*)d_in[4];
    const float* ar1 = (const float*)d_in[5];
    const float* b1  = (const float*)d_in[6];
    const float* W2  = (const float*)d_in[7];
    const float* al2 = (const float*)d_in[8];
    const float* ar2 = (const float*)d_in[9];
    const float* b2  = (const float*)d_in[10];
    float* out = (float*)d_out;

    // ---- workspace layout (float-offset based; every chunk 16B-aligned) ----
    float* ws = (float*)d_ws;
    size_t off = 0;
    unsigned short* Zh  = (unsigned short*)(ws + off); off += (size_t)NREL * MPAD * C1 / 2;
    unsigned short* hbh = (unsigned short*)(ws + off); off += (size_t)NNODES * C1 / 2;
    unsigned short* P1  = (unsigned short*)(ws + off); off += (size_t)NREL * (C1/16) * (IND/32) * 512 / 2;
    unsigned short* PV  = (unsigned short*)(ws + off); off += (size_t)NREL * 4 * 16 * 512 / 2;
    float* el  = ws + off; off += (size_t)NREL * NNODES * NHEADS;
    float* er  = ws + off; off += (size_t)NREL * NNODES * NHEADS;
    float* el2 = ws + off; off += (size_t)NREL * NNODES * NHEADS;
    float* er2 = ws + off; off += (size_t)NREL * NNODES * NHEADS;
    unsigned* cnt = (unsigned*)(ws + off); off += (size_t)NREL * NNODES;
    int* buck  = (int*)(ws + off); off += (size_t)NREL * NNODES * CAP;
    float* tabs    = ws + off; off += 24 * C1;     // layer-2 attn projection tables
    float* biasout = ws + off; off += OUTD;        // 0.25 * sum_{r,h} b2

    const int TB = 256;

    // ---- merged front-end: memset, then {bucket_fill | packs | tables | bias} ----
    hipMemsetAsync(cnt, 0, (size_t)NREL * NNODES * sizeof(unsigned), stream);
    prep_kernel<<<PREP_BLOCKS, TB, 0, stream>>>(src, dst, cnt, buck,
                                                W1, P1, W2, PV, al2, ar2, b2,
                                                tabs, biasout);

    // ================= layer 1 (+ folded layer-2 logits) =================
    {
        dim3 grid(MPAD / 64, NREL);
        mfma_gemm<IND, C1><<<grid, 256, 0, stream>>>(x, P1, al1, ar1, Zh, el, er);
    }
    gat_gather1<<<NNODES / 4, 256, 0, stream>>>(cnt, buck, el, er, Zh, b1, tabs,
                                                hbh, el2, er2);

    // ================= layer 2 (no z2 GEMM: aggregate-then-multiply) =================
    gat_gather2f<<<NNODES / 8, 512, 0, stream>>>(cnt, buck, el2, er2, hbh, PV, biasout, out);
}